// Round 11
// baseline (224.012 us; speedup 1.0000x reference)
//
#include <hip/hip_runtime.h>

// TextCNN: B=128, S=512, E=300, H=64, k_i = i/2+2 in [2,33].
// Virtual-im2col bf16 MFMA GEMM, fused gather, E-split LDS staging.
//   == R9 structure (conv_fused ~86.5us, GBASE B layout) + A+B dist-1 prefetch ==
//   Grid: 128 b x 6 t-slices (96 rows each) = 768 blocks = 3/CU resident.
//   Block: 4 waves = 2-way M-split (p) x 2-way j(K)-split (jh), acc[3][4].
//   R10 lesson: contiguous-B + pointer-bump REGRESSED (-6us) despite -2% VALU:
//   chained addresses serialize load issue. Keep per-j br+const addressing
//   (dependency-free, issues early). VALU count != criticality.
//   R11: the uncovered latency is the A ds_read (~120cy) consumed in-step.
//   Rotate BOTH A (3x bf16x8 from LDS) and B (NG x bf16x8 from L2) one step
//   ahead: next-step loads issue before current MFMAs. Addresses are all
//   base + unroll-const. Tail prefetch reads (jhi,0): B lands in-workspace
//   (<=860KB+4KB < 1MB wsF offset); A reaches LDS row 128 -> At padded to
//   130 rows (41.6KB; discarded values, residency still 3/CU reg-capped).
//   Live ~= 48 acc + 56 frag (2 sets) + addr ~= 130 unified < 170 cap (256,3).
//   Epilogue: 2-phase jh reduce in LDS (store, add), tanh + masked max.
// ws layout: [0, 860KB) wsB bf16 | [1MB, +192KB) wsF f32 (128*64*6).

#define SS     512
#define EE     300
#define HH     64
#define KMAXW  33
#define LP     160          // LDS half-row pitch in elems (320 B = 20 chunks)
#define HALFSZ 215040       // wsB elems per E-half (420 steps * 512)
#define RP     68           // epilogue reduce pitch (floats)

typedef __attribute__((ext_vector_type(8))) short bf16x8;
typedef __attribute__((ext_vector_type(4))) float f32x4;

__device__ __forceinline__ unsigned short f2bf(float f) {
    unsigned u = __float_as_uint(f);
    unsigned r = ((u >> 16) & 1u) + 0x7FFFu;   // round-to-nearest-even
    return (unsigned short)((u + r) >> 16);
}

// ---- Kernel 1: repack Wconv (f32 [64][33][300]) -> wsB bf16, fragment order.
// step id within (half, group): j*5+u, u indexes 32-elem sub-blocks of the 160-elem half.
__global__ __launch_bounds__(256) void prep_weights(const float* __restrict__ Wconv,
                                                    unsigned short* __restrict__ wsB) {
    int idx = blockIdx.x * 256 + threadIdx.x;      // < 430080
    int r    = idx & 7;
    int lane = (idx >> 3) & 63;
    int gs   = idx >> 9;                           // < 840
    int h    = gs / 420;
    int ww   = gs - h * 420;
    int g, t;
    if      (ww < 45)  { g = 0; t = ww;       }
    else if (ww < 130) { g = 1; t = ww - 45;  }
    else if (ww < 255) { g = 2; t = ww - 130; }
    else               { g = 3; t = ww - 255; }
    int j = t / 5, u = t - j * 5;
    int i  = g * 16 + (lane & 15);
    int ki = i / 2 + 2;
    int kk = (lane >> 4) * 8 + r;
    int e  = h * 160 + u * 32 + kk;
    float v = 0.f;
    if (e < EE && j < ki) v = Wconv[(i * KMAXW + j) * EE + e];
    wsB[idx] = f2bf(v);
}

#define MFMA(A, Bf, C) __builtin_amdgcn_mfma_f32_16x16x32_bf16((A), (Bf), (C), 0, 0, 0)

// One j-segment: groups g in [G0,4) active (segment lies in a G-pure j range).
// ar0 = At + (p*48+m)*LP + q*8 (lane's A base); bp = wsB half base + lane*8.
// Distance-1 prefetch on BOTH operands: step s's MFMAs run on regs loaded in
// step s-1; next-step A (LDS) and B (L2) loads issue before the MFMAs.
// All load addresses are base + unroll-constant (no pointer chaining -- R10).
template<int G0>
__device__ __forceinline__ void seg(const unsigned short* __restrict__ ar0,
                                    int jlo, int jhi,
                                    const unsigned short* __restrict__ bp,
                                    f32x4 acc[3][4]) {
    constexpr int GBASE[4] = {0, 45, 130, 255};
    bf16x8 bc[4], ac[3];
    #pragma unroll
    for (int g = G0; g < 4; ++g)
        bc[g] = *(const bf16x8*)(bp + (GBASE[g] + jlo * 5) * 512);
    #pragma unroll
    for (int t = 0; t < 3; ++t)
        ac[t] = *(const bf16x8*)(ar0 + jlo * LP + t * (16 * LP));
    #pragma unroll 1
    for (int j = jlo; j < jhi; ++j) {
        const unsigned short* ar = ar0 + j * LP;
        const unsigned short* br = bp + j * 5 * 512;
        #pragma unroll
        for (int u = 0; u < 5; ++u) {
            bf16x8 bn[4], an[3];
            #pragma unroll
            for (int g = G0; g < 4; ++g)     // next step: (j,u+1); at u=4 == (j+1,0)
                bn[g] = *(const bf16x8*)(br + (GBASE[g] + u + 1) * 512);
            {
                const unsigned short* arn = ar + ((u == 4) ? LP : 0);
                const int un = (u == 4) ? 0 : (u + 1);
                #pragma unroll
                for (int t = 0; t < 3; ++t)
                    an[t] = *(const bf16x8*)(arn + t * (16 * LP) + un * 32);
            }
            #pragma unroll
            for (int t = 0; t < 3; ++t)
                #pragma unroll
                for (int g = G0; g < 4; ++g)
                    acc[t][g] = MFMA(ac[t], bc[g], acc[t][g]);
            #pragma unroll
            for (int g = G0; g < 4; ++g) bc[g] = bn[g];
            #pragma unroll
            for (int t = 0; t < 3; ++t) ac[t] = an[t];
        }
    }
}

// ---- Kernel 2: fused gather + GEMM + cross-wave reduce + tanh + masked max.
__global__ __launch_bounds__(256, 3) void conv_fused(const int* __restrict__ x,
                                                     const float* __restrict__ emb,
                                                     const unsigned short* __restrict__ wsB,
                                                     const float* __restrict__ bconv,
                                                     float* __restrict__ wsF) {
    // 130 rows: rows 128..129 are prefetch-overrun pad (values discarded).
    __shared__ __align__(16) unsigned short At[130 * LP];   // 41600 B

    int b     = blockIdx.x / 6;
    int slice = blockIdx.x - b * 6;
    int t0    = slice * 96;

    int lane = threadIdx.x & 63;
    int w    = threadIdx.x >> 6;
    int p    = w >> 1;                 // M-half: 3 tiles of 16 rows
    int jh   = w & 1;                  // j-range half
    int m = lane & 15, q = lane >> 4;

    f32x4 acc[3][4] = {};

    const unsigned short* ar0 = At + (p * 48 + m) * LP + q * 8;

    for (int eh = 0; eh < 2; ++eh) {
        if (eh) __syncthreads();       // all reads of previous half complete

        // Stage 128 half-rows (96 + 32 halo), f32 -> bf16, zero-padded.
        #pragma unroll
        for (int it = 0; it < 10; ++it) {
            int idx = threadIdx.x + it * 256;      // < 2560
            int rr = idx / 20, c = idx - rr * 20;
            int srow = t0 + rr;
            bf16x8 v = {0, 0, 0, 0, 0, 0, 0, 0};
            if (srow < SS) {
                int tok = x[b * SS + srow];
                const float* ep = emb + (long)tok * EE + eh * 160 + c * 8;
                if (eh == 0 || c < 17) {
                    float4 f0 = ((const float4*)ep)[0];
                    float4 f1 = ((const float4*)ep)[1];
                    v[0] = f2bf(f0.x); v[1] = f2bf(f0.y); v[2] = f2bf(f0.z); v[3] = f2bf(f0.w);
                    v[4] = f2bf(f1.x); v[5] = f2bf(f1.y); v[6] = f2bf(f1.z); v[7] = f2bf(f1.w);
                } else if (c == 17) {  // elems 296..299 valid
                    float4 f0 = ((const float4*)ep)[0];
                    v[0] = f2bf(f0.x); v[1] = f2bf(f0.y); v[2] = f2bf(f0.z); v[3] = f2bf(f0.w);
                }
            }
            *(bf16x8*)&At[rr * LP + c * 8] = v;
        }
        __syncthreads();

        const unsigned short* bp = wsB + eh * HALFSZ + lane * 8;
        // j-regions by active-group count: [0,9):4g, [9,17):3g, [17,25):2g, [25,33):1g.
        // jh0: [0,9)+[25,31) = 36+6 = 42 units; jh1: [9,25)+[31,33) = 40+2 = 42.
        // (1 unit = 5u x 3t = 15 MFMA) -> 630 MFMA/wave/half, exact SIMD balance.
        if (jh == 0) {
            seg<0>(ar0, 0, 9,  bp, acc);
            seg<3>(ar0, 25, 31, bp, acc);
        } else {
            seg<1>(ar0, 9, 17, bp, acc);
            seg<2>(ar0, 17, 25, bp, acc);
            seg<3>(ar0, 31, 33, bp, acc);
        }
    }

    // ---- Epilogue: 2-phase jh-partial reduce in LDS, then tanh + masked max.
    __syncthreads();                                  // done reading At
    float* red  = (float*)At;                         // [96][RP] = 26112 B
    float* red2 = red + 96 * RP;                      // [4][64]  = 1024 B (27136 <= 41600)

    // C/D map: col = m (filter in group), row = p*48 + t*16 + q*4 + r.
    if (jh == 0) {
        #pragma unroll
        for (int t = 0; t < 3; ++t)
            #pragma unroll
            for (int g = 0; g < 4; ++g)
                #pragma unroll
                for (int r = 0; r < 4; ++r)
                    red[(p * 48 + t * 16 + q * 4 + r) * RP + g * 16 + m] = acc[t][g][r];
    }
    __syncthreads();
    if (jh == 1) {
        #pragma unroll
        for (int t = 0; t < 3; ++t)
            #pragma unroll
            for (int g = 0; g < 4; ++g)
                #pragma unroll
                for (int r = 0; r < 4; ++r)
                    red[(p * 48 + t * 16 + q * 4 + r) * RP + g * 16 + m] += acc[t][g][r];
    }
    __syncthreads();

    int f  = threadIdx.x & 63;                        // filter
    int rg = threadIdx.x >> 6;                        // row group (24 rows each)
    int ki = (f >> 1) + 2;
    int tmax = SS - ki;
    float bc = bconv[f];
    float mx = -3.0e38f;
    #pragma unroll 1
    for (int rr = 0; rr < 24; ++rr) {
        int row = rg * 24 + rr;
        int tb  = t0 + row;
        float v = tanhf(red[row * RP + f] + bc);
        if (tb <= tmax) mx = fmaxf(mx, v);
    }
    red2[rg * 64 + f] = mx;
    __syncthreads();
    if (threadIdx.x < 64) {
        float v = fmaxf(fmaxf(red2[f], red2[64 + f]),
                        fmaxf(red2[128 + f], red2[192 + f]));
        wsF[(b * HH + f) * 6 + slice] = v;
    }
}

// ---- Kernel 3: max over 6 partials, linear, sigmoid. 128 blocks x 64 thr.
__global__ __launch_bounds__(64) void final_linear(const float* __restrict__ wsF,
                                                   const float* __restrict__ Wlin,
                                                   const float* __restrict__ blin,
                                                   float* __restrict__ out) {
    int b = blockIdx.x;
    int i = threadIdx.x;
    const float* pp = wsF + (b * HH + i) * 6;
    float mx = pp[0];
    #pragma unroll
    for (int j = 1; j < 6; ++j) mx = fmaxf(mx, pp[j]);
    float v = mx * Wlin[i];
    #pragma unroll
    for (int off = 1; off < 64; off <<= 1) v += __shfl_xor(v, off);
    if (i == 0) out[b] = 1.0f / (1.0f + expf(-(v + blin[0])));
}

extern "C" void kernel_launch(void* const* d_in, const int* in_sizes, int n_in,
                              void* d_out, int out_size, void* d_ws, size_t ws_size,
                              hipStream_t stream) {
    const int*   x     = (const int*)d_in[0];
    const float* emb   = (const float*)d_in[1];
    const float* Wconv = (const float*)d_in[2];
    const float* bconv = (const float*)d_in[3];
    const float* Wlin  = (const float*)d_in[4];
    const float* blin  = (const float*)d_in[5];
    float* out = (float*)d_out;

    unsigned short* wsB = (unsigned short*)d_ws;
    float*          wsF = (float*)((char*)d_ws + (1u << 20));

    prep_weights<<<1680, 256, 0, stream>>>(Wconv, wsB);
    conv_fused<<<768, 256, 0, stream>>>(x, emb, wsB, bconv, wsF);
    final_linear<<<128, 64, 0, stream>>>(wsF, Wlin, blin, out);
}

// Round 12
// 173.564 us; speedup vs baseline: 1.2907x; 1.2907x over previous
//
#include <hip/hip_runtime.h>

// TextCNN: B=128, S=512, E=300, H=64, k_i = i/2+2 in [2,33].
// Virtual-im2col bf16 MFMA GEMM, fused gather, E-split LDS staging.
//   == R9 structure (best: conv_fused 86.5us) + j-loop unroll 2 ==
//   Grid: 128 b x 6 t-slices (96 rows each) = 768 blocks = 3/CU resident.
//   Block: 4 waves = 2-way M-split (p) x 2-way j(K)-split (jh), acc[3][4].
//   Register B-prefetch dist-1 (R8, +20us): covers B L2 latency partially.
//   R11 lesson: hand-rotating the A (LDS) operand regressed 54us -- the
//   compiler's native lgkmcnt pipelining inside the unrolled u-body is
//   better than explicit rotation; only cross-back-edge GLOBAL loads need
//   manual prefetch. R12: keep R9 body, j-loop unroll 1 -> 2 so the
//   scheduler can hoist iteration k+1's A/B loads above iteration k's
//   MFMAs (compiler-mediated deeper pipeline, counted waitcnt). Unified
//   regs 132 + modest growth < 170 cap of (256,3).
//   Epilogue: 2-phase jh reduce in LDS (store, add), tanh + masked max.
// ws layout: [0, 860KB) wsB bf16 | [1MB, +192KB) wsF f32 (128*64*6).

#define SS     512
#define EE     300
#define HH     64
#define KMAXW  33
#define LP     160          // LDS half-row pitch in elems (320 B = 20 chunks)
#define HALFSZ 215040       // wsB elems per E-half (420 steps * 512)
#define RP     68           // epilogue reduce pitch (floats)

typedef __attribute__((ext_vector_type(8))) short bf16x8;
typedef __attribute__((ext_vector_type(4))) float f32x4;

__device__ __forceinline__ unsigned short f2bf(float f) {
    unsigned u = __float_as_uint(f);
    unsigned r = ((u >> 16) & 1u) + 0x7FFFu;   // round-to-nearest-even
    return (unsigned short)((u + r) >> 16);
}

// ---- Kernel 1: repack Wconv (f32 [64][33][300]) -> wsB bf16, fragment order.
// step id within (half, group): j*5+u, u indexes 32-elem sub-blocks of the 160-elem half.
__global__ __launch_bounds__(256) void prep_weights(const float* __restrict__ Wconv,
                                                    unsigned short* __restrict__ wsB) {
    int idx = blockIdx.x * 256 + threadIdx.x;      // < 430080
    int r    = idx & 7;
    int lane = (idx >> 3) & 63;
    int gs   = idx >> 9;                           // < 840
    int h    = gs / 420;
    int ww   = gs - h * 420;
    int g, t;
    if      (ww < 45)  { g = 0; t = ww;       }
    else if (ww < 130) { g = 1; t = ww - 45;  }
    else if (ww < 255) { g = 2; t = ww - 130; }
    else               { g = 3; t = ww - 255; }
    int j = t / 5, u = t - j * 5;
    int i  = g * 16 + (lane & 15);
    int ki = i / 2 + 2;
    int kk = (lane >> 4) * 8 + r;
    int e  = h * 160 + u * 32 + kk;
    float v = 0.f;
    if (e < EE && j < ki) v = Wconv[(i * KMAXW + j) * EE + e];
    wsB[idx] = f2bf(v);
}

#define MFMA(A, Bf, C) __builtin_amdgcn_mfma_f32_16x16x32_bf16((A), (Bf), (C), 0, 0, 0)

// One j-segment: groups g in [G0,4) are active (segment must lie in a G-pure j range).
// ar0 = At + (p*48+m)*LP + q*8 (lane's A base); bp = wsB half base + lane*8.
// Register B-prefetch: bc holds step s's frags, bn issues step s+1's loads
// before the MFMAs -> B L2 latency hides under the step issue. A loads are
// in-step (compiler pipelines them natively -- R11 lesson). j-loop unroll 2
// lets the scheduler hoist iteration k+1's loads above iteration k's MFMAs.
template<int G0>
__device__ __forceinline__ void seg(const unsigned short* __restrict__ ar0,
                                    int jlo, int jhi,
                                    const unsigned short* __restrict__ bp,
                                    f32x4 acc[3][4]) {
    constexpr int GBASE[4] = {0, 45, 130, 255};
    bf16x8 bc[4];
    #pragma unroll
    for (int g = G0; g < 4; ++g)
        bc[g] = *(const bf16x8*)(bp + (GBASE[g] + jlo * 5) * 512);
    #pragma unroll 2
    for (int j = jlo; j < jhi; ++j) {
        const unsigned short* ar = ar0 + j * LP;
        const unsigned short* br = bp + j * 5 * 512;
        #pragma unroll
        for (int u = 0; u < 5; ++u) {
            bf16x8 bn[4];
            #pragma unroll
            for (int g = G0; g < 4; ++g)     // next step (u+1; at u=4 -> (j+1,0))
                bn[g] = *(const bf16x8*)(br + (GBASE[g] + u + 1) * 512);
            #pragma unroll
            for (int t = 0; t < 3; ++t) {
                bf16x8 a = *(const bf16x8*)(ar + t * (16 * LP) + u * 32);
                #pragma unroll
                for (int g = G0; g < 4; ++g)
                    acc[t][g] = MFMA(a, bc[g], acc[t][g]);
            }
            #pragma unroll
            for (int g = G0; g < 4; ++g) bc[g] = bn[g];
        }
    }
}

// ---- Kernel 2: fused gather + GEMM + cross-wave reduce + tanh + masked max.
__global__ __launch_bounds__(256, 3) void conv_fused(const int* __restrict__ x,
                                                     const float* __restrict__ emb,
                                                     const unsigned short* __restrict__ wsB,
                                                     const float* __restrict__ bconv,
                                                     float* __restrict__ wsF) {
    __shared__ __align__(16) unsigned short At[128 * LP];   // 40960 B

    int b     = blockIdx.x / 6;
    int slice = blockIdx.x - b * 6;
    int t0    = slice * 96;

    int lane = threadIdx.x & 63;
    int w    = threadIdx.x >> 6;
    int p    = w >> 1;                 // M-half: 3 tiles of 16 rows
    int jh   = w & 1;                  // j-range half
    int m = lane & 15, q = lane >> 4;

    f32x4 acc[3][4] = {};

    const unsigned short* ar0 = At + (p * 48 + m) * LP + q * 8;

    for (int eh = 0; eh < 2; ++eh) {
        if (eh) __syncthreads();       // all reads of previous half complete

        // Stage 128 half-rows (96 + 32 halo), f32 -> bf16, zero-padded.
        // idx*16B dests are contiguous per wave -> 2-way bank (free) writes.
        #pragma unroll
        for (int it = 0; it < 10; ++it) {
            int idx = threadIdx.x + it * 256;      // < 2560
            int rr = idx / 20, c = idx - rr * 20;
            int srow = t0 + rr;
            bf16x8 v = {0, 0, 0, 0, 0, 0, 0, 0};
            if (srow < SS) {
                int tok = x[b * SS + srow];
                const float* ep = emb + (long)tok * EE + eh * 160 + c * 8;
                if (eh == 0 || c < 17) {
                    float4 f0 = ((const float4*)ep)[0];
                    float4 f1 = ((const float4*)ep)[1];
                    v[0] = f2bf(f0.x); v[1] = f2bf(f0.y); v[2] = f2bf(f0.z); v[3] = f2bf(f0.w);
                    v[4] = f2bf(f1.x); v[5] = f2bf(f1.y); v[6] = f2bf(f1.z); v[7] = f2bf(f1.w);
                } else if (c == 17) {  // elems 296..299 valid
                    float4 f0 = ((const float4*)ep)[0];
                    v[0] = f2bf(f0.x); v[1] = f2bf(f0.y); v[2] = f2bf(f0.z); v[3] = f2bf(f0.w);
                }
            }
            *(bf16x8*)&At[rr * LP + c * 8] = v;
        }
        __syncthreads();

        const unsigned short* bp = wsB + eh * HALFSZ + lane * 8;
        // j-regions by active-group count: [0,9):4g, [9,17):3g, [17,25):2g, [25,33):1g.
        // jh0: [0,9)+[25,31) = 36+6 = 42 units; jh1: [9,25)+[31,33) = 40+2 = 42.
        // (1 unit = 5u x 3t = 15 MFMA) -> 630 MFMA/wave/half, exact SIMD balance.
        if (jh == 0) {
            seg<0>(ar0, 0, 9,  bp, acc);
            seg<3>(ar0, 25, 31, bp, acc);
        } else {
            seg<1>(ar0, 9, 17, bp, acc);
            seg<2>(ar0, 17, 25, bp, acc);
            seg<3>(ar0, 31, 33, bp, acc);
        }
    }

    // ---- Epilogue: 2-phase jh-partial reduce in LDS, then tanh + masked max.
    __syncthreads();                                  // done reading At
    float* red  = (float*)At;                         // [96][RP] = 26112 B
    float* red2 = red + 96 * RP;                      // [4][64]  = 1024 B (27136 <= 40960)

    // C/D map: col = m (filter in group), row = p*48 + t*16 + q*4 + r.
    if (jh == 0) {
        #pragma unroll
        for (int t = 0; t < 3; ++t)
            #pragma unroll
            for (int g = 0; g < 4; ++g)
                #pragma unroll
                for (int r = 0; r < 4; ++r)
                    red[(p * 48 + t * 16 + q * 4 + r) * RP + g * 16 + m] = acc[t][g][r];
    }
    __syncthreads();
    if (jh == 1) {
        #pragma unroll
        for (int t = 0; t < 3; ++t)
            #pragma unroll
            for (int g = 0; g < 4; ++g)
                #pragma unroll
                for (int r = 0; r < 4; ++r)
                    red[(p * 48 + t * 16 + q * 4 + r) * RP + g * 16 + m] += acc[t][g][r];
    }
    __syncthreads();

    int f  = threadIdx.x & 63;                        // filter
    int rg = threadIdx.x >> 6;                        // row group (24 rows each)
    int ki = (f >> 1) + 2;
    int tmax = SS - ki;
    float bc = bconv[f];
    float mx = -3.0e38f;
    #pragma unroll 1
    for (int rr = 0; rr < 24; ++rr) {
        int row = rg * 24 + rr;
        int tb  = t0 + row;
        float v = tanhf(red[row * RP + f] + bc);
        if (tb <= tmax) mx = fmaxf(mx, v);
    }
    red2[rg * 64 + f] = mx;
    __syncthreads();
    if (threadIdx.x < 64) {
        float v = fmaxf(fmaxf(red2[f], red2[64 + f]),
                        fmaxf(red2[128 + f], red2[192 + f]));
        wsF[(b * HH + f) * 6 + slice] = v;
    }
}

// ---- Kernel 3: max over 6 partials, linear, sigmoid. 128 blocks x 64 thr.
__global__ __launch_bounds__(64) void final_linear(const float* __restrict__ wsF,
                                                   const float* __restrict__ Wlin,
                                                   const float* __restrict__ blin,
                                                   float* __restrict__ out) {
    int b = blockIdx.x;
    int i = threadIdx.x;
    const float* pp = wsF + (b * HH + i) * 6;
    float mx = pp[0];
    #pragma unroll
    for (int j = 1; j < 6; ++j) mx = fmaxf(mx, pp[j]);
    float v = mx * Wlin[i];
    #pragma unroll
    for (int off = 1; off < 64; off <<= 1) v += __shfl_xor(v, off);
    if (i == 0) out[b] = 1.0f / (1.0f + expf(-(v + blin[0])));
}

extern "C" void kernel_launch(void* const* d_in, const int* in_sizes, int n_in,
                              void* d_out, int out_size, void* d_ws, size_t ws_size,
                              hipStream_t stream) {
    const int*   x     = (const int*)d_in[0];
    const float* emb   = (const float*)d_in[1];
    const float* Wconv = (const float*)d_in[2];
    const float* bconv = (const float*)d_in[3];
    const float* Wlin  = (const float*)d_in[4];
    const float* blin  = (const float*)d_in[5];
    float* out = (float*)d_out;

    unsigned short* wsB = (unsigned short*)d_ws;
    float*          wsF = (float*)((char*)d_ws + (1u << 20));

    prep_weights<<<1680, 256, 0, stream>>>(Wconv, wsB);
    conv_fused<<<768, 256, 0, stream>>>(x, emb, wsB, bconv, wsF);
    final_linear<<<128, 64, 0, stream>>>(wsF, Wlin, blin, out);
}

// Round 13
// 163.211 us; speedup vs baseline: 1.3725x; 1.0634x over previous
//
#include <hip/hip_runtime.h>

// TextCNN: B=128, S=512, E=300, H=64, k_i = i/2+2 in [2,33].
// Virtual-im2col bf16 MFMA GEMM, fused gather, E-split LDS staging.
//   == R9 base (best: conv_fused 86.5us) + setprio(T5) + tanh-after-max ==
//   Grid: 128 b x 6 t-slices (96 rows each) = 768 blocks = 3/CU resident.
//   Block: 4 waves = 2-way M-split (p) x 2-way j(K)-split (jh), acc[3][4].
//   Register B-prefetch dist-1 (R8, +20us): the ONLY scheduling intervention
//   that paid. Ledger: R10 pointer-chain -6us, R11 A-rotation -54us, R12
//   unroll-2 -6us -> compiler's native lgkmcnt pipelining wins inside the
//   u-body; only cross-back-edge GLOBAL loads need manual prefetch.
//   R13a: s_setprio(1) around each 12-MFMA cluster. 12 waves/CU at genuinely
//   different phases (3 blocks x 4 divergent j-paths) -> T5's prereq holds
//   (m191 attn-like, not m190 lockstep-GEMM).
//   R13b: epilogue tanh AFTER masked max (monotone fn commutes with max;
//   bc uniform): 24 tanhf/thread -> 1. Fully-masked -> tanh(-inf) = -1,
//   still below every real tanh value.
//   Pipe budget at 86.5us (208K cyc/CU): MFMA 35%, LDS ~50%, L2-B 22%,
//   VALU 20% -- mixed latency-bound, occupancy reg-capped at 3 waves/SIMD.
//   Epilogue: 2-phase jh reduce in LDS (store, add), masked max + tanh.
// ws layout: [0, 860KB) wsB bf16 | [1MB, +192KB) wsF f32 (128*64*6).

#define SS     512
#define EE     300
#define HH     64
#define KMAXW  33
#define LP     160          // LDS half-row pitch in elems (320 B = 20 chunks)
#define HALFSZ 215040       // wsB elems per E-half (420 steps * 512)
#define RP     68           // epilogue reduce pitch (floats)

typedef __attribute__((ext_vector_type(8))) short bf16x8;
typedef __attribute__((ext_vector_type(4))) float f32x4;

__device__ __forceinline__ unsigned short f2bf(float f) {
    unsigned u = __float_as_uint(f);
    unsigned r = ((u >> 16) & 1u) + 0x7FFFu;   // round-to-nearest-even
    return (unsigned short)((u + r) >> 16);
}

// ---- Kernel 1: repack Wconv (f32 [64][33][300]) -> wsB bf16, fragment order.
// step id within (half, group): j*5+u, u indexes 32-elem sub-blocks of the 160-elem half.
__global__ __launch_bounds__(256) void prep_weights(const float* __restrict__ Wconv,
                                                    unsigned short* __restrict__ wsB) {
    int idx = blockIdx.x * 256 + threadIdx.x;      // < 430080
    int r    = idx & 7;
    int lane = (idx >> 3) & 63;
    int gs   = idx >> 9;                           // < 840
    int h    = gs / 420;
    int ww   = gs - h * 420;
    int g, t;
    if      (ww < 45)  { g = 0; t = ww;       }
    else if (ww < 130) { g = 1; t = ww - 45;  }
    else if (ww < 255) { g = 2; t = ww - 130; }
    else               { g = 3; t = ww - 255; }
    int j = t / 5, u = t - j * 5;
    int i  = g * 16 + (lane & 15);
    int ki = i / 2 + 2;
    int kk = (lane >> 4) * 8 + r;
    int e  = h * 160 + u * 32 + kk;
    float v = 0.f;
    if (e < EE && j < ki) v = Wconv[(i * KMAXW + j) * EE + e];
    wsB[idx] = f2bf(v);
}

#define MFMA(A, Bf, C) __builtin_amdgcn_mfma_f32_16x16x32_bf16((A), (Bf), (C), 0, 0, 0)

// One j-segment: groups g in [G0,4) are active (segment must lie in a G-pure j range).
// ar0 = At + (p*48+m)*LP + q*8 (lane's A base); bp = wsB half base + lane*8.
// Register B-prefetch: bc holds step s's frags, bn issues step s+1's loads
// before the MFMAs -> B L2 latency hides under the 12-MFMA step issue.
// setprio(1) wraps the MFMA cluster: desynced waves yield issue to the
// MFMA-burst wave (T5; prereq = phase-diverse waves, which jh/p split gives).
template<int G0>
__device__ __forceinline__ void seg(const unsigned short* __restrict__ ar0,
                                    int jlo, int jhi,
                                    const unsigned short* __restrict__ bp,
                                    f32x4 acc[3][4]) {
    constexpr int GBASE[4] = {0, 45, 130, 255};
    bf16x8 bc[4];
    #pragma unroll
    for (int g = G0; g < 4; ++g)
        bc[g] = *(const bf16x8*)(bp + (GBASE[g] + jlo * 5) * 512);
    #pragma unroll 1
    for (int j = jlo; j < jhi; ++j) {
        const unsigned short* ar = ar0 + j * LP;
        const unsigned short* br = bp + j * 5 * 512;
        #pragma unroll
        for (int u = 0; u < 5; ++u) {
            bf16x8 bn[4];
            #pragma unroll
            for (int g = G0; g < 4; ++g)     // next step (u+1; at u=4 -> (j+1,0))
                bn[g] = *(const bf16x8*)(br + (GBASE[g] + u + 1) * 512);
            __builtin_amdgcn_s_setprio(1);
            #pragma unroll
            for (int t = 0; t < 3; ++t) {
                bf16x8 a = *(const bf16x8*)(ar + t * (16 * LP) + u * 32);
                #pragma unroll
                for (int g = G0; g < 4; ++g)
                    acc[t][g] = MFMA(a, bc[g], acc[t][g]);
            }
            __builtin_amdgcn_s_setprio(0);
            #pragma unroll
            for (int g = G0; g < 4; ++g) bc[g] = bn[g];
        }
    }
}

// ---- Kernel 2: fused gather + GEMM + cross-wave reduce + masked max + tanh.
__global__ __launch_bounds__(256, 3) void conv_fused(const int* __restrict__ x,
                                                     const float* __restrict__ emb,
                                                     const unsigned short* __restrict__ wsB,
                                                     const float* __restrict__ bconv,
                                                     float* __restrict__ wsF) {
    __shared__ __align__(16) unsigned short At[128 * LP];   // 40960 B

    int b     = blockIdx.x / 6;
    int slice = blockIdx.x - b * 6;
    int t0    = slice * 96;

    int lane = threadIdx.x & 63;
    int w    = threadIdx.x >> 6;
    int p    = w >> 1;                 // M-half: 3 tiles of 16 rows
    int jh   = w & 1;                  // j-range half
    int m = lane & 15, q = lane >> 4;

    f32x4 acc[3][4] = {};

    const unsigned short* ar0 = At + (p * 48 + m) * LP + q * 8;

    for (int eh = 0; eh < 2; ++eh) {
        if (eh) __syncthreads();       // all reads of previous half complete

        // Stage 128 half-rows (96 + 32 halo), f32 -> bf16, zero-padded.
        // idx*16B dests are contiguous per wave -> 2-way bank (free) writes.
        #pragma unroll
        for (int it = 0; it < 10; ++it) {
            int idx = threadIdx.x + it * 256;      // < 2560
            int rr = idx / 20, c = idx - rr * 20;
            int srow = t0 + rr;
            bf16x8 v = {0, 0, 0, 0, 0, 0, 0, 0};
            if (srow < SS) {
                int tok = x[b * SS + srow];
                const float* ep = emb + (long)tok * EE + eh * 160 + c * 8;
                if (eh == 0 || c < 17) {
                    float4 f0 = ((const float4*)ep)[0];
                    float4 f1 = ((const float4*)ep)[1];
                    v[0] = f2bf(f0.x); v[1] = f2bf(f0.y); v[2] = f2bf(f0.z); v[3] = f2bf(f0.w);
                    v[4] = f2bf(f1.x); v[5] = f2bf(f1.y); v[6] = f2bf(f1.z); v[7] = f2bf(f1.w);
                } else if (c == 17) {  // elems 296..299 valid
                    float4 f0 = ((const float4*)ep)[0];
                    v[0] = f2bf(f0.x); v[1] = f2bf(f0.y); v[2] = f2bf(f0.z); v[3] = f2bf(f0.w);
                }
            }
            *(bf16x8*)&At[rr * LP + c * 8] = v;
        }
        __syncthreads();

        const unsigned short* bp = wsB + eh * HALFSZ + lane * 8;
        // j-regions by active-group count: [0,9):4g, [9,17):3g, [17,25):2g, [25,33):1g.
        // jh0: [0,9)+[25,31) = 36+6 = 42 units; jh1: [9,25)+[31,33) = 40+2 = 42.
        // (1 unit = 5u x 3t = 15 MFMA) -> 630 MFMA/wave/half, exact SIMD balance.
        if (jh == 0) {
            seg<0>(ar0, 0, 9,  bp, acc);
            seg<3>(ar0, 25, 31, bp, acc);
        } else {
            seg<1>(ar0, 9, 17, bp, acc);
            seg<2>(ar0, 17, 25, bp, acc);
            seg<3>(ar0, 31, 33, bp, acc);
        }
    }

    // ---- Epilogue: 2-phase jh-partial reduce in LDS, then masked max + tanh.
    __syncthreads();                                  // done reading At
    float* red  = (float*)At;                         // [96][RP] = 26112 B
    float* red2 = red + 96 * RP;                      // [4][64]  = 1024 B (27136 <= 40960)

    // C/D map: col = m (filter in group), row = p*48 + t*16 + q*4 + r.
    if (jh == 0) {
        #pragma unroll
        for (int t = 0; t < 3; ++t)
            #pragma unroll
            for (int g = 0; g < 4; ++g)
                #pragma unroll
                for (int r = 0; r < 4; ++r)
                    red[(p * 48 + t * 16 + q * 4 + r) * RP + g * 16 + m] = acc[t][g][r];
    }
    __syncthreads();
    if (jh == 1) {
        #pragma unroll
        for (int t = 0; t < 3; ++t)
            #pragma unroll
            for (int g = 0; g < 4; ++g)
                #pragma unroll
                for (int r = 0; r < 4; ++r)
                    red[(p * 48 + t * 16 + q * 4 + r) * RP + g * 16 + m] += acc[t][g][r];
    }
    __syncthreads();

    int f  = threadIdx.x & 63;                        // filter
    int rg = threadIdx.x >> 6;                        // row group (24 rows each)
    int ki = (f >> 1) + 2;
    int tmax = SS - ki;
    float bc = bconv[f];
    float mx = -3.0e38f;
    #pragma unroll 1
    for (int rr = 0; rr < 24; ++rr) {
        int row = rg * 24 + rr;
        int tb  = t0 + row;
        float y = red[row * RP + f];
        if (tb <= tmax) mx = fmaxf(mx, y);
    }
    // tanh is monotone and bc is row-uniform: max(tanh(y+bc)) == tanh(max(y)+bc).
    // Fully-masked threads: tanh(-3e38+bc) = -1 <= every real tanh -> harmless.
    mx = tanhf(mx + bc);
    red2[rg * 64 + f] = mx;
    __syncthreads();
    if (threadIdx.x < 64) {
        float v = fmaxf(fmaxf(red2[f], red2[64 + f]),
                        fmaxf(red2[128 + f], red2[192 + f]));
        wsF[(b * HH + f) * 6 + slice] = v;
    }
}

// ---- Kernel 3: max over 6 partials, linear, sigmoid. 128 blocks x 64 thr.
__global__ __launch_bounds__(64) void final_linear(const float* __restrict__ wsF,
                                                   const float* __restrict__ Wlin,
                                                   const float* __restrict__ blin,
                                                   float* __restrict__ out) {
    int b = blockIdx.x;
    int i = threadIdx.x;
    const float* pp = wsF + (b * HH + i) * 6;
    float mx = pp[0];
    #pragma unroll
    for (int j = 1; j < 6; ++j) mx = fmaxf(mx, pp[j]);
    float v = mx * Wlin[i];
    #pragma unroll
    for (int off = 1; off < 64; off <<= 1) v += __shfl_xor(v, off);
    if (i == 0) out[b] = 1.0f / (1.0f + expf(-(v + blin[0])));
}

extern "C" void kernel_launch(void* const* d_in, const int* in_sizes, int n_in,
                              void* d_out, int out_size, void* d_ws, size_t ws_size,
                              hipStream_t stream) {
    const int*   x     = (const int*)d_in[0];
    const float* emb   = (const float*)d_in[1];
    const float* Wconv = (const float*)d_in[2];
    const float* bconv = (const float*)d_in[3];
    const float* Wlin  = (const float*)d_in[4];
    const float* blin  = (const float*)d_in[5];
    float* out = (float*)d_out;

    unsigned short* wsB = (unsigned short*)d_ws;
    float*          wsF = (float*)((char*)d_ws + (1u << 20));

    prep_weights<<<1680, 256, 0, stream>>>(Wconv, wsB);
    conv_fused<<<768, 256, 0, stream>>>(x, emb, wsB, bconv, wsF);
    final_linear<<<128, 64, 0, stream>>>(wsF, Wlin, blin, out);
}